// Round 3
// baseline (93.182 us; speedup 1.0000x reference)
//
#include <hip/hip_runtime.h>

#define KNBR 32
#define G 8
#define OBS 16
#define KP 8          // neighbors per thread
#define TPQ 4         // threads per query
#define BLOCK 128

// ws layout: [0, 256) bytes = 64 derived fp32 constants (SGPR-loadable)
//            [256, 256 + N*16) = points repacked as float4 (16B aligned)
#define CST_CY   0
#define CST_INC  8
#define CST_CONE 16
#define CST_DA   24
#define CST_DB   32
#define CST_EA   40
#define CST_EB   48
#define CST_EC   56

// Prologue: repack points to float4 + compute folded constants -0.5*log2e/(r^2+eps)
__global__ __launch_bounds__(256) void gib_prep(
    const float* __restrict__ p3, float4* __restrict__ p4, int N,
    const float* __restrict__ cy_radius,
    const float* __restrict__ disk_radius,
    const float* __restrict__ disk_width,
    const float* __restrict__ cone_radius,
    const float* __restrict__ cone_inc,
    const float* __restrict__ ellip_radii,
    float* __restrict__ cst)
{
    const int i = blockIdx.x * 256 + threadIdx.x;
    if (i < N) {
        p4[i] = make_float4(p3[3 * i], p3[3 * i + 1], p3[3 * i + 2], 0.f);
    }
    if (blockIdx.x == 0 && threadIdx.x < G) {
        const int t = threadIdx.x;
        const float NL2E = -0.5f * 1.44269504088896340736f;
        const float EPS = 1e-8f;
        float r;
        r = cy_radius[t];          cst[CST_CY + t]   = NL2E / (r * r + EPS);
        cst[CST_INC + t] = cone_inc[t];
        r = cone_radius[t];        cst[CST_CONE + t] = NL2E / (r * r + EPS);
        r = disk_radius[t];        cst[CST_DA + t]   = NL2E / (r * r + EPS);
        r = disk_width[t];         cst[CST_DB + t]   = NL2E / (r * r + EPS);
        r = ellip_radii[3 * t + 0]; cst[CST_EA + t]  = NL2E / (r * r + EPS);
        r = ellip_radii[3 * t + 1]; cst[CST_EB + t]  = NL2E / (r * r + EPS);
        r = ellip_radii[3 * t + 2]; cst[CST_EC + t]  = NL2E / (r * r + EPS);
    }
}

__global__ __launch_bounds__(BLOCK) void gib_kernel(
    const float4* __restrict__ points4,
    const float*  __restrict__ q_coords,
    const int*    __restrict__ sidx,
    const float*  __restrict__ cst,      // 64 uniform constants -> s_load
    const float*  __restrict__ lambdas,
    float* __restrict__ out,
    int M)
{
    __shared__ float  s_lam[4 * G * OBS];      // (32,16) row-major, 2 KB
    __shared__ float4 s_data[BLOCK * KP];      // compacted neighbors, 16 KB

    const float EPS = 1e-8f;
    const int t = threadIdx.x;

    // stage lambdas (512 floats, 4 per thread)
    #pragma unroll
    for (int i = 0; i < 4; i++) s_lam[t + i * BLOCK] = lambdas[t + i * BLOCK];
    __syncthreads();

    const int gid = blockIdx.x * BLOCK + t;
    const int m   = gid >> 2;       // query index
    const int sub = t & 3;          // which quarter of K
    if (m >= M) return;

    const float qx = q_coords[3 * m + 0];
    const float qy = q_coords[3 * m + 1];
    const float qz = q_coords[3 * m + 2];

    const int4* ip = (const int4*)(sidx + (size_t)m * KNBR + sub * KP);
    int4 i0 = ip[0], i1 = ip[1];
    int id[KP] = {i0.x, i0.y, i0.z, i0.w, i1.x, i1.y, i1.z, i1.w};

    // gather + mask test + compact active neighbors into private LDS slots
    int cnt = 0;
    #pragma unroll
    for (int j = 0; j < KP; j++) {
        float4 p = points4[id[j]];
        float rx = p.x - qx, ry = p.y - qy, rz = p.z - qz;
        float a = rx * rx, b = ry * ry, c = rz * rz;
        if (a + b + c <= 1.0f) {                 // REACH^2 = 1
            s_data[t * KP + cnt] = make_float4(a, b, c, rz);
            cnt++;
        }
    }

    // uniform constants -> SGPRs (one s_load batch, hoisted by compiler)
    float acc0[G], acc1[G], acc2[G], acc3[G];
    #pragma unroll
    for (int g = 0; g < G; g++) { acc0[g] = 0.f; acc1[g] = 0.f; acc2[g] = 0.f; acc3[g] = 0.f; }

    #pragma unroll
    for (int j = 0; j < KP; j++) {
        if (j < cnt) {
            float4 v = s_data[t * KP + j];
            float x2 = v.x, y2 = v.y, z2 = v.z, zz = v.w;
            float xy2 = x2 + y2;
            float rxy = __builtin_amdgcn_sqrtf(xy2 + EPS);
            #pragma unroll
            for (int g = 0; g < G; g++) {
                acc0[g] += __builtin_amdgcn_exp2f(xy2 * cst[CST_CY + g]);
                float d = __builtin_fmaf(-cst[CST_INC + g], zz, rxy);
                acc1[g] += __builtin_amdgcn_exp2f(d * d * cst[CST_CONE + g]);
                acc2[g] += __builtin_amdgcn_exp2f(
                    __builtin_fmaf(xy2, cst[CST_DA + g], z2 * cst[CST_DB + g]));
                acc3[g] += __builtin_amdgcn_exp2f(
                    __builtin_fmaf(x2, cst[CST_EA + g],
                    __builtin_fmaf(y2, cst[CST_EB + g], z2 * cst[CST_EC + g])));
            }
        }
    }

    // reduce across the 4 lanes of this query (butterfly), order: cy, cone, disk, ellip
    float acc[4 * G];
    #pragma unroll
    for (int g = 0; g < G; g++) {
        acc[g] = acc0[g]; acc[G + g] = acc1[g];
        acc[2 * G + g] = acc2[g]; acc[3 * G + g] = acc3[g];
    }
    #pragma unroll
    for (int j = 0; j < 4 * G; j++) {
        acc[j] += __shfl_xor(acc[j], 1);
        acc[j] += __shfl_xor(acc[j], 2);
    }

    // epilogue: out[m, sub*4 .. sub*4+3] = (acc . lambda[:, cols]) / K
    float o0 = 0.f, o1 = 0.f, o2 = 0.f, o3 = 0.f;
    #pragma unroll
    for (int j = 0; j < 4 * G; j++) {
        float4 l = *(const float4*)(s_lam + j * OBS + sub * 4);
        o0 = __builtin_fmaf(acc[j], l.x, o0);
        o1 = __builtin_fmaf(acc[j], l.y, o1);
        o2 = __builtin_fmaf(acc[j], l.z, o2);
        o3 = __builtin_fmaf(acc[j], l.w, o3);
    }
    const float s = 1.0f / (float)KNBR;
    float4 o = make_float4(o0 * s, o1 * s, o2 * s, o3 * s);
    *(float4*)(out + (size_t)m * OBS + sub * 4) = o;
}

extern "C" void kernel_launch(void* const* d_in, const int* in_sizes, int n_in,
                              void* d_out, int out_size, void* d_ws, size_t ws_size,
                              hipStream_t stream) {
    const float* points      = (const float*)d_in[0];
    const float* q_coords    = (const float*)d_in[1];
    const int*   sidx        = (const int*)  d_in[2];
    const float* cy_radius   = (const float*)d_in[3];
    const float* disk_radius = (const float*)d_in[4];
    const float* disk_width  = (const float*)d_in[5];
    const float* cone_radius = (const float*)d_in[6];
    const float* cone_inc    = (const float*)d_in[7];
    const float* ellip_radii = (const float*)d_in[8];
    const float* lambdas     = (const float*)d_in[9];
    float* out = (float*)d_out;

    const int N = in_sizes[0] / 3;
    const int M = in_sizes[1] / 3;

    float*  cst = (float*)d_ws;
    float4* p4  = (float4*)((char*)d_ws + 256);

    gib_prep<<<(N + 255) / 256, 256, 0, stream>>>(
        points, p4, N, cy_radius, disk_radius, disk_width,
        cone_radius, cone_inc, ellip_radii, cst);

    const int grid = (M * TPQ + BLOCK - 1) / BLOCK;
    gib_kernel<<<grid, BLOCK, 0, stream>>>(p4, q_coords, sidx, cst, lambdas, out, M);
}